// Round 16
// baseline (591.208 us; speedup 1.0000x reference)
//
#include <hip/hip_runtime.h>
#include <cstdint>
#include <cstddef>

constexpr int N_  = 20480;
constexpr int E_  = 163840;
constexpr int G_  = 512;
constexpr int D_  = 128;
constexpr int H_  = 4;
constexpr int R_  = 8;
constexpr int L_  = 4;
constexpr int HK_ = 512;   // H*D
constexpr int NPG_ = N_ / G_; // 40

typedef short short8 __attribute__((ext_vector_type(8)));
typedef float f32x4 __attribute__((ext_vector_type(4)));
typedef unsigned short u16;
typedef unsigned int u32;

__device__ inline u16 bfr(float f) {  // fp32 -> bf16 RNE
  u32 u = __builtin_bit_cast(u32, f);
  return (u16)((u + 0x7fffu + ((u >> 16) & 1u)) >> 16);
}
__device__ inline float bf2f(u32 lo16) { return __builtin_bit_cast(float, lo16 << 16); }
__device__ inline float lrelu(float v) { return v >= 0.f ? v : 0.2f * v; }

// ---------------- fused zero: countsR (RN) + countsN (N) ----------------
__global__ void k_zero2(int* __restrict__ cR, int* __restrict__ cN) {
  int i = blockIdx.x * blockDim.x + threadIdx.x;
  if (i < R_ * N_) cR[i] = 0;
  else if (i < R_ * N_ + N_) cN[i - R_ * N_] = 0;
}

// ---------------- fused count: rel-CSR + dst-CSR ----------------
__global__ void k_count_both(const int* __restrict__ dst, const int* __restrict__ et,
                             int* __restrict__ cR, int* __restrict__ cN) {
  int e = blockIdx.x * blockDim.x + threadIdx.x;
  if (e < E_) {
    int d = dst[e];
    atomicAdd(&cR[et[e] * N_ + d], 1);
    atomicAdd(&cN[d], 1);
  }
}

// ---------------- fused per-block sums ----------------
__global__ void k_bsum2(const int* __restrict__ cR, const int* __restrict__ cN,
                        int* __restrict__ bsumR, int* __restrict__ bsumN) {
  int b = blockIdx.x;
  const int* src = (b < 160) ? &cR[b * 1024] : &cN[(b - 160) * 1024];
  int t = threadIdx.x;
  const int4 v = *(const int4*)&src[t * 4];
  int s = v.x + v.y + v.z + v.w;
#pragma unroll
  for (int o = 32; o; o >>= 1) s += __shfl_down(s, o, 64);
  __shared__ int ws_[4];
  if ((t & 63) == 0) ws_[t >> 6] = s;
  __syncthreads();
  if (t == 0) {
    int tot = ws_[0] + ws_[1] + ws_[2] + ws_[3];
    if (b < 160) bsumR[b] = tot; else bsumN[b - 160] = tot;
  }
}

// ---------------- fused block-sum scan + totals (r6 lesson: totals MUST be written) ----------------
__global__ void k_bscan2(int* __restrict__ bsumR, int* __restrict__ bsumN,
                         int* __restrict__ totR, int* __restrict__ totN) {
  __shared__ int shR[160];
  __shared__ int shN[20];
  int t = threadIdx.x;
  if (t < 160) shR[t] = bsumR[t];
  if (t < 20) shN[t] = bsumN[t];
  __syncthreads();
  if (t == 0) {
    int run = 0;
    for (int i = 0; i < 160; ++i) { int v = shR[i]; shR[i] = run; run += v; }
    totR[0] = run;   // = E
    int run2 = 0;
    for (int i = 0; i < 20; ++i) { int v = shN[i]; shN[i] = run2; run2 += v; }
    totN[0] = run2;  // = E
  }
  __syncthreads();
  if (t < 160) bsumR[t] = shR[t];
  if (t < 20) bsumN[t] = shN[t];
}

// ---------------- fused full scan write ----------------
__global__ void k_scan32(const int* __restrict__ cR, const int* __restrict__ cN,
                         const int* __restrict__ bsumR, const int* __restrict__ bsumN,
                         int* __restrict__ ipR, int* __restrict__ curR,
                         int* __restrict__ ipN, int* __restrict__ curN) {
  __shared__ int ts[256];
  int b = blockIdx.x;
  const int* c;
  int off0;
  int* indptr;
  int* cursor;
  int lb;
  if (b < 160) { c = cR; off0 = bsumR[b]; indptr = ipR; cursor = curR; lb = b; }
  else { c = cN; off0 = bsumN[b - 160]; indptr = ipN; cursor = curN; lb = b - 160; }
  int t = threadIdx.x;
  int base = lb * 1024 + t * 4;
  const int4 v = *(const int4*)&c[base];
  int s0 = v.x, s01 = v.x + v.y, s012 = s01 + v.z, s = s012 + v.w;
  ts[t] = s;
  __syncthreads();
#pragma unroll
  for (int o = 1; o < 256; o <<= 1) {
    int add = (t >= o) ? ts[t - o] : 0;
    __syncthreads();
    ts[t] += add;
    __syncthreads();
  }
  int off = off0 + (t ? ts[t - 1] : 0);
  int4 o4 = make_int4(off, off + s0, off + s01, off + s012);
  *(int4*)&indptr[base] = o4;
  *(int4*)&cursor[base] = o4;
}

// ---------------- fused scatter: rel slots (slotOf,srcR) + dst-CSR (esortD) ----------------
__global__ void k_scatter_both(const int* __restrict__ dst, const int* __restrict__ et,
                               const int* __restrict__ src, int* __restrict__ curR,
                               int* __restrict__ curN, int* __restrict__ slotOf,
                               int* __restrict__ srcR, int* __restrict__ esortD) {
  int e = blockIdx.x * blockDim.x + threadIdx.x;
  if (e < E_) {
    int d = dst[e];
    int p = atomicAdd(&curR[et[e] * N_ + d], 1);
    slotOf[e] = p;
    srcR[p] = src[e];
    int p2 = atomicAdd(&curN[d], 1);
    esortD[p2] = e;
  }
}

// ---------------- WQK for ALL layers: wave per (l,r,d) row ----------------
__global__ __launch_bounds__(256) void k_wqk_all(const float* __restrict__ W,
                                                 const float* __restrict__ Q,
                                                 const float* __restrict__ Km,
                                                 float* __restrict__ WQK) {
  int gw = (blockIdx.x * 256 + threadIdx.x) >> 6;  // 0..L*R*D-1 = 4095
  int lane = threadIdx.x & 63;
  int d = gw & 127, r = (gw >> 7) & 7, l = gw >> 10;
  const float* wrow = W + (((size_t)l * R_ + r) * D_ + d) * HK_;
  const float* Ql = Q + (size_t)l * HK_ * H_;
  const float* Kl = Km + (size_t)l * HK_ * H_;
  float acc[8] = {0.f, 0.f, 0.f, 0.f, 0.f, 0.f, 0.f, 0.f};
#pragma unroll
  for (int it = 0; it < 8; ++it) {
    int k = it * 64 + lane;
    float w = wrow[k];
    const float4 qv = *(const float4*)&Ql[k * 4];
    const float4 kv = *(const float4*)&Kl[k * 4];
    acc[0] += w * qv.x; acc[1] += w * qv.y; acc[2] += w * qv.z; acc[3] += w * qv.w;
    acc[4] += w * kv.x; acc[5] += w * kv.y; acc[6] += w * kv.z; acc[7] += w * kv.w;
  }
#pragma unroll
  for (int o = 32; o; o >>= 1)
#pragma unroll
    for (int j = 0; j < 8; ++j) acc[j] += __shfl_down(acc[j], o, 64);
  if (lane == 0) {
#pragma unroll
    for (int h = 0; h < 4; ++h) {
      WQK[((size_t)l * D_ + d) * 64 + r * 4 + h] = acc[h];
      WQK[((size_t)l * D_ + d) * 64 + 32 + r * 4 + h] = acc[4 + h];
    }
  }
}

// ---------------- fused embed + layer-0 q,k (32 nodes/block) ----------------
__global__ __launch_bounds__(256) void k_embed_qk(
    const int* __restrict__ xn, const float* __restrict__ emb,
    const float* __restrict__ WQK, float* __restrict__ x, u16* __restrict__ xb,
    float* __restrict__ q, float* __restrict__ kk) {
  __shared__ float xs[32][129];
  __shared__ float wq[128][64];
  __shared__ int xnl[32];
  const int t = threadIdx.x;
  const int n0 = blockIdx.x * 32;
  if (t < 32) xnl[t] = xn[n0 + t];
#pragma unroll
  for (int p = 0; p < 8; ++p) {
    int idx = t + p * 256;
    int row = idx >> 4, c4 = (idx & 15) * 4;
    *(float4*)&wq[row][c4] = *(const float4*)&WQK[row * 64 + c4];
  }
  __syncthreads();
#pragma unroll
  for (int p = 0; p < 16; ++p) {      // 4096 elems of x
    int idx = t + p * 256;
    int node = idx >> 7, d = idx & 127;
    float v = emb[xnl[node] * D_ + d];
    xs[node][d] = v;
    x[(size_t)(n0 + node) * D_ + d] = v;
    xb[(size_t)(n0 + node) * D_ + d] = bfr(v);
  }
  __syncthreads();
  const int node = t >> 3, cq = t & 7;
  float s[8];
#pragma unroll
  for (int j = 0; j < 8; ++j) s[j] = 0.f;
  for (int k = 0; k < 128; ++k) {
    float xv = xs[node][k];
#pragma unroll
    for (int j = 0; j < 8; ++j) s[j] = fmaf(xv, wq[k][cq * 8 + j], s[j]);
  }
#pragma unroll
  for (int j = 0; j < 8; ++j) {
    int c = cq * 8 + j;
    if (c < 32) q[(size_t)(n0 + node) * 32 + c] = s[j];
    else        kk[(size_t)(n0 + node) * 32 + (c - 32)] = s[j];
  }
}

// ---------------- fused attention softmax: wave per dst node, normalized aw out ----------------
__global__ __launch_bounds__(256) void k_attn(
    const int* __restrict__ ipN, const int* __restrict__ esD,
    const int* __restrict__ src, const int* __restrict__ et,
    const float* __restrict__ q, const float* __restrict__ kk,
    const int* __restrict__ slotOf, float* __restrict__ aw) {
  int n = blockIdx.x * 4 + (threadIdx.x >> 6);
  int lane = threadIdx.x & 63;
  int j0 = ipN[n], j1 = ipN[n + 1];
  int deg = j1 - j0;
  if (deg == 0) return;            // wave-uniform
  int h = lane & 3;
  if (deg <= 16) {                 // fast path (covers most nodes)
    int ei = lane >> 2;
    float a = -3.4e38f;
    int slot = 0;
    if (ei < deg) {
      int e = esD[j0 + ei];
      int r = et[e];
      slot = slotOf[e];
      a = lrelu(q[(size_t)n * 32 + r * 4 + h] + kk[(size_t)src[e] * 32 + r * 4 + h]);
    }
    float m = a;
#pragma unroll
    for (int o = 4; o < 64; o <<= 1) m = fmaxf(m, __shfl_xor(m, o, 64));
    float ex = (ei < deg) ? expf(a - m) : 0.f;
    float s = ex;
#pragma unroll
    for (int o = 4; o < 64; o <<= 1) s += __shfl_xor(s, o, 64);
    if (ei < deg) aw[(size_t)slot * 4 + h] = ex * (0.25f / (s + 1e-16f));
    return;
  }
  // general path (rare)
  int nch = (deg + 15) >> 4;
  float m = -3.4e38f;
  for (int c = 0; c < nch; ++c) {
    int ei = c * 16 + (lane >> 2);
    if (ei < deg) {
      int e = esD[j0 + ei];
      int r = et[e];
      float a = lrelu(q[(size_t)n * 32 + r * 4 + h] + kk[(size_t)src[e] * 32 + r * 4 + h]);
      m = fmaxf(m, a);
    }
  }
#pragma unroll
  for (int o = 4; o < 64; o <<= 1) m = fmaxf(m, __shfl_xor(m, o, 64));
  float s = 0.f;
  for (int c = 0; c < nch; ++c) {
    int ei = c * 16 + (lane >> 2);
    if (ei < deg) {
      int e = esD[j0 + ei];
      int r = et[e];
      float a = lrelu(q[(size_t)n * 32 + r * 4 + h] + kk[(size_t)src[e] * 32 + r * 4 + h]);
      float ex = expf(a - m);
      s += ex;
      aw[(size_t)slotOf[e] * 4 + h] = ex;
    }
  }
#pragma unroll
  for (int o = 4; o < 64; o <<= 1) s += __shfl_xor(s, o, 64);
  float inv = 0.25f / (s + 1e-16f);
  for (int c = 0; c < nch; ++c) {
    int ei = c * 16 + (lane >> 2);
    if (ei < deg) {
      int e = esD[j0 + ei];
      aw[(size_t)slotOf[e] * 4 + h] *= inv;
    }
  }
}

// W fp32 [L][R][D][HK] -> wt bf16 [L][R][HK][D]  (all layers, z = l*R+r)
__global__ void k_cvt_w_all(const float* __restrict__ W, u16* __restrict__ wt) {
  __shared__ u16 tile[64][65];
  const int z = blockIdx.z, k0 = blockIdx.y * 64, c0 = blockIdx.x * 64;
  const int t = threadIdx.x;
  const int tk = t >> 4, tc4 = (t & 15) * 4;
  const float* Wz = W + (size_t)z * D_ * HK_;
  u16* wz = wt + (size_t)z * HK_ * D_;
#pragma unroll
  for (int p = 0; p < 4; ++p) {
    int krow = tk + p * 16;
    const float4 v = *(const float4*)&Wz[(size_t)(k0 + krow) * HK_ + c0 + tc4];
    tile[tc4 + 0][krow] = bfr(v.x);
    tile[tc4 + 1][krow] = bfr(v.y);
    tile[tc4 + 2][krow] = bfr(v.z);
    tile[tc4 + 3][krow] = bfr(v.w);
  }
  __syncthreads();
#pragma unroll
  for (int p = 0; p < 4; ++p) {
    int crow = tk + p * 16;
    uint2 o;
    o.x = (u32)tile[crow][tc4 + 0] | ((u32)tile[crow][tc4 + 1] << 16);
    o.y = (u32)tile[crow][tc4 + 2] | ((u32)tile[crow][tc4 + 3] << 16);
    *(uint2*)&wz[(size_t)(c0 + crow) * D_ + k0 + tc4] = o;
  }
}

// ---------------- k_node: weighted-gather Y + 32-panel MFMA + fused epilogue ----------------
// out[n,:] = sum_r sum_h Y[n,r,h,:] @ W[r][:,h*128..], Y = sum_e aw[e,h]*x[src_e,:].
// 32 nodes/block, 256 thr (4 waves). No mbuf: messages never materialized.
__global__ __launch_bounds__(256, 2) void k_node(
    const u16* __restrict__ xb, const u16* __restrict__ wt,   // wt: layer base [R][HK][D]
    const int* __restrict__ ipR, const int* __restrict__ srcR,
    const float* __restrict__ aw, const float* __restrict__ Bl,
    const float* __restrict__ WQK, int doqk,
    float* __restrict__ xout, u16* __restrict__ xbout,
    float* __restrict__ q, float* __restrict__ kk) {
  __shared__ u16 Y[4][32 * 128];       // 32 KB (4 x 8KB, XOR-swizzled rows of 256B)
  __shared__ float xrow[32][132];      // 16.9 KB (pad 132: bank-shift + 16B align)
  float* wqs = (float*)&Y[0][0];       // overlays Y after final MFMA
  const int t = threadIdx.x;
  const int n0 = blockIdx.x * 32;
  const int nl = t >> 3, sl = t & 7;   // gather role: node-local, 16-dim slice
  const int w = t >> 6, lane = t & 63;
  const int l15 = lane & 15, l4 = lane >> 4;
  f32x4 acc[2][2];                     // [rowfrag i][colfrag fi]; col f = w + 4*fi
#pragma unroll
  for (int i = 0; i < 2; ++i)
#pragma unroll
    for (int fi = 0; fi < 2; ++fi) acc[i][fi] = (f32x4){0.f, 0.f, 0.f, 0.f};

  for (int r = 0; r < R_; ++r) {
    // ---- gather: Y[n,r,h,sl*16..] accumulated in registers (slots contiguous) ----
    int j0 = ipR[r * N_ + n0 + nl];
    int j1 = ipR[r * N_ + n0 + nl + 1];
    float y[4][16];
#pragma unroll
    for (int h = 0; h < 4; ++h)
#pragma unroll
      for (int d = 0; d < 16; ++d) y[h][d] = 0.f;
    for (int j = j0; j < j1; ++j) {
      int s = srcR[j];
      const float4 a4 = *(const float4*)(aw + (size_t)j * 4);
      const uint4 xv0 = *(const uint4*)(xb + (size_t)s * 128 + sl * 16);
      const uint4 xv1 = *(const uint4*)(xb + (size_t)s * 128 + sl * 16 + 8);
      float xf[16];
      xf[0] = bf2f(xv0.x & 0xffffu); xf[1] = bf2f(xv0.x >> 16);
      xf[2] = bf2f(xv0.y & 0xffffu); xf[3] = bf2f(xv0.y >> 16);
      xf[4] = bf2f(xv0.z & 0xffffu); xf[5] = bf2f(xv0.z >> 16);
      xf[6] = bf2f(xv0.w & 0xffffu); xf[7] = bf2f(xv0.w >> 16);
      xf[8] = bf2f(xv1.x & 0xffffu); xf[9] = bf2f(xv1.x >> 16);
      xf[10] = bf2f(xv1.y & 0xffffu); xf[11] = bf2f(xv1.y >> 16);
      xf[12] = bf2f(xv1.z & 0xffffu); xf[13] = bf2f(xv1.z >> 16);
      xf[14] = bf2f(xv1.w & 0xffffu); xf[15] = bf2f(xv1.w >> 16);
#pragma unroll
      for (int d = 0; d < 16; ++d) {
        y[0][d] = fmaf(a4.x, xf[d], y[0][d]);
        y[1][d] = fmaf(a4.y, xf[d], y[1][d]);
        y[2][d] = fmaf(a4.z, xf[d], y[2][d]);
        y[3][d] = fmaf(a4.w, xf[d], y[3][d]);
      }
    }
    __syncthreads();   // previous r's MFMA done reading Y
    // ---- write Y tiles (bf16, XOR-swizzled) ----
#pragma unroll
    for (int h = 0; h < 4; ++h) {
      uint4 o0, o1;
      o0.x = (u32)bfr(y[h][0]) | ((u32)bfr(y[h][1]) << 16);
      o0.y = (u32)bfr(y[h][2]) | ((u32)bfr(y[h][3]) << 16);
      o0.z = (u32)bfr(y[h][4]) | ((u32)bfr(y[h][5]) << 16);
      o0.w = (u32)bfr(y[h][6]) | ((u32)bfr(y[h][7]) << 16);
      o1.x = (u32)bfr(y[h][8]) | ((u32)bfr(y[h][9]) << 16);
      o1.y = (u32)bfr(y[h][10]) | ((u32)bfr(y[h][11]) << 16);
      o1.z = (u32)bfr(y[h][12]) | ((u32)bfr(y[h][13]) << 16);
      o1.w = (u32)bfr(y[h][14]) | ((u32)bfr(y[h][15]) << 16);
      char* base = (char*)Y[h] + nl * 256;
      *(uint4*)(base + ((sl * 32 + 0) ^ ((nl & 7) << 4))) = o0;
      *(uint4*)(base + ((sl * 32 + 16) ^ ((nl & 7) << 4))) = o1;
    }
    __syncthreads();   // Y visible
    // ---- MFMA: 4 h-panels; B from L2-hot Wtb ----
    const u16* wrp = wt + (size_t)r * HK_ * D_;
#pragma unroll
    for (int h = 0; h < 4; ++h) {
      short8 bv[2][4];
#pragma unroll
      for (int fi = 0; fi < 2; ++fi)
#pragma unroll
        for (int ks = 0; ks < 4; ++ks) {
          int c = h * 128 + (w + 4 * fi) * 16 + l15;
          bv[fi][ks] = *(const short8*)(wrp + (size_t)c * 128 + ks * 32 + l4 * 8);
        }
#pragma unroll
      for (int ks = 0; ks < 4; ++ks) {
        short8 av[2];
#pragma unroll
        for (int i = 0; i < 2; ++i) {
          int row = i * 16 + l15;
          av[i] = *(const short8*)((char*)Y[h] + row * 256 +
                    ((l4 * 16 + ks * 64) ^ ((row & 7) << 4)));
        }
#pragma unroll
        for (int i = 0; i < 2; ++i)
#pragma unroll
          for (int fi = 0; fi < 2; ++fi)
            // swapped operands: lane holds row = i*16+l15, col = (w+4*fi)*16 + l4*4 + rg
            acc[i][fi] = __builtin_amdgcn_mfma_f32_16x16x32_bf16(bv[fi][ks], av[i],
                                                                 acc[i][fi], 0, 0, 0);
      }
    }
  }
  __syncthreads();   // all MFMA done; Y region free for wqs overlay
  // ---- epilogue: bias + relu -> xrow ----
#pragma unroll
  for (int i = 0; i < 2; ++i)
#pragma unroll
    for (int fi = 0; fi < 2; ++fi) {
      int row = i * 16 + l15;
      int cb = (w + 4 * fi) * 16 + l4 * 4;
      float4 o;
      o.x = fmaxf(acc[i][fi][0] + Bl[cb + 0], 0.f);
      o.y = fmaxf(acc[i][fi][1] + Bl[cb + 1], 0.f);
      o.z = fmaxf(acc[i][fi][2] + Bl[cb + 2], 0.f);
      o.w = fmaxf(acc[i][fi][3] + Bl[cb + 3], 0.f);
      *(float4*)&xrow[row][cb] = o;
    }
  if (doqk) {
#pragma unroll
    for (int p = 0; p < 32; ++p) wqs[t + p * 256] = WQK[t + p * 256];
  }
  __syncthreads();   // xrow + wqs visible
  // ---- write x (fp32) + xb (bf16 next layer) ----
#pragma unroll
  for (int pp = 0; pp < 8; ++pp) {
    int idx = t + pp * 256;         // 2048 pairs
    int row = idx >> 6, c2 = (idx & 63) * 2;
    float v0 = xrow[row][c2], v1 = xrow[row][c2 + 1];
    *(float2*)(xout + (size_t)(n0 + row) * D_ + c2) = make_float2(v0, v1);
    *((u32*)(xbout + (size_t)(n0 + row) * D_ + c2)) = (u32)bfr(v0) | ((u32)bfr(v1) << 16);
  }
  // ---- next-layer q,k ----
  if (doqk) {
    const int node = t >> 3, cq = t & 7;
    float s[8];
#pragma unroll
    for (int j = 0; j < 8; ++j) s[j] = 0.f;
    for (int k2 = 0; k2 < 128; ++k2) {
      float xv = xrow[node][k2];
#pragma unroll
      for (int j = 0; j < 8; ++j) s[j] = fmaf(xv, wqs[k2 * 64 + cq * 8 + j], s[j]);
    }
#pragma unroll
    for (int j = 0; j < 8; ++j) {
      int c = cq * 8 + j;
      if (c < 32) q[(size_t)(n0 + node) * 32 + c] = s[j];
      else        kk[(size_t)(n0 + node) * 32 + (c - 32)] = s[j];
    }
  }
}

// ---------------- graph mean-pool ----------------
__global__ void k_pool(const float* __restrict__ x, float* __restrict__ pooled) {
  int i = blockIdx.x * blockDim.x + threadIdx.x; // G*D
  if (i >= G_ * D_) return;
  int d = i & 127, g = i >> 7;
  float s = 0.f;
  for (int j = 0; j < NPG_; ++j) s += x[(size_t)(g * NPG_ + j) * D_ + d];
  pooled[i] = s * (1.0f / NPG_);
}

// ---------------- head MLP ----------------
__global__ void k_head(const float* __restrict__ pooled, const float* __restrict__ fc1w,
                       const float* __restrict__ fc1b, const float* __restrict__ polw,
                       const float* __restrict__ polb, const float* __restrict__ valw,
                       const float* __restrict__ valb, float* __restrict__ out) {
  int g = blockIdx.x;
  int t = threadIdx.x; // 64
  __shared__ float hb[64];
  const float* p = pooled + (size_t)g * D_;
  float s = fc1b[t];
  for (int d = 0; d < D_; ++d) s += p[d] * fc1w[d * 64 + t];
  hb[t] = fmaxf(s, 0.f);
  __syncthreads();
  if (t < 7) {
    float s2 = polb[t];
    for (int j = 0; j < 64; ++j) s2 += hb[j] * polw[j * 7 + t];
    out[g * 7 + t] = s2;
  } else if (t == 7) {
    float s2 = valb[0];
    for (int j = 0; j < 64; ++j) s2 += hb[j] * valw[j];
    out[G_ * 7 + g] = tanhf(s2);
  }
}

extern "C" void kernel_launch(void* const* d_in, const int* in_sizes, int n_in,
                              void* d_out, int out_size, void* d_ws, size_t ws_size,
                              hipStream_t stream) {
  (void)in_sizes; (void)n_in; (void)out_size;
  const int*   x_nodes = (const int*)d_in[0];
  const int*   eidx    = (const int*)d_in[1];
  const int*   etype   = (const int*)d_in[2];
  const float* emb     = (const float*)d_in[4];
  const float* W       = (const float*)d_in[5];
  const float* Q       = (const float*)d_in[6];
  const float* Km      = (const float*)d_in[7];
  const float* B       = (const float*)d_in[8];
  const float* fc1w    = (const float*)d_in[9];
  const float* fc1b    = (const float*)d_in[10];
  const float* polw    = (const float*)d_in[11];
  const float* polb    = (const float*)d_in[12];
  const float* valw    = (const float*)d_in[13];
  const float* valb    = (const float*)d_in[14];
  float* out = (float*)d_out;
  const int* srcA = eidx;        // edge_index[0,:]
  const int* dstA = eidx + E_;   // edge_index[1,:]

  char* p = (char*)d_ws;
  size_t used = 0;
  auto carve = [&](size_t bytes) {
    char* q = p;
    size_t adv = (bytes + 255) & ~(size_t)255;
    p += adv;
    used += adv;
    return q;
  };
  float* x_cur  = (float*)carve((size_t)N_ * D_ * 4);            // 10.5 MB
  u16*   xbf_a  = (u16*)carve((size_t)N_ * D_ * 2);              // 5.2 MB
  u16*   xbf_b  = (u16*)carve((size_t)N_ * D_ * 2);              // 5.2 MB
  float* qbuf   = (float*)carve((size_t)N_ * 32 * 4);            // 2.6 MB
  float* kbuf   = (float*)carve((size_t)N_ * 32 * 4);            // 2.6 MB
  float* awbuf  = (float*)carve((size_t)E_ * H_ * 4);            // 2.6 MB
  float* WQKb   = (float*)carve((size_t)L_ * D_ * 64 * 4);       // 131 KB
  u16*   Wtb    = (u16*)carve((size_t)L_ * R_ * HK_ * D_ * 2);   // 4.2 MB
  float* pooled = (float*)carve((size_t)G_ * D_ * 4);
  int* countsR  = (int*)carve((size_t)R_ * N_ * 4);
  int* cursorR  = (int*)carve((size_t)R_ * N_ * 4);
  int* indptrR  = (int*)carve((size_t)(R_ * N_ + 1) * 4);
  int* slotOf   = (int*)carve((size_t)E_ * 4);
  int* srcR     = (int*)carve((size_t)E_ * 4);
  int* countsN  = (int*)carve((size_t)N_ * 4);
  int* cursorN  = (int*)carve((size_t)N_ * 4);
  int* indptrN  = (int*)carve((size_t)(N_ + 1) * 4);
  int* esortD   = (int*)carve((size_t)E_ * 4);
  int* bsumR    = (int*)carve((size_t)160 * 4);
  int* bsumN    = (int*)carve((size_t)32 * 4);
  if (used > ws_size) return;  // defensive: fail via poisoned output, not OOB crash

  constexpr int RN = R_ * N_;          // 163840

  // ---- fused CSR builds + one-time precomputes ----
  k_zero2<<<(RN + N_ + 255) / 256, 256, 0, stream>>>(countsR, countsN);
  k_count_both<<<E_ / 256, 256, 0, stream>>>(dstA, etype, countsR, countsN);
  k_bsum2<<<180, 256, 0, stream>>>(countsR, countsN, bsumR, bsumN);
  k_bscan2<<<1, 256, 0, stream>>>(bsumR, bsumN, indptrR + RN, indptrN + N_);
  k_scan32<<<180, 256, 0, stream>>>(countsR, countsN, bsumR, bsumN,
                                    indptrR, cursorR, indptrN, cursorN);
  k_scatter_both<<<E_ / 256, 256, 0, stream>>>(dstA, etype, srcA, cursorR, cursorN,
                                               slotOf, srcR, esortD);
  k_wqk_all<<<(L_ * R_ * D_ * 64) / 256, 256, 0, stream>>>(W, Q, Km, WQKb);
  k_cvt_w_all<<<dim3(HK_ / 64, D_ / 64, L_ * R_), 256, 0, stream>>>(W, Wtb);
  k_embed_qk<<<N_ / 32, 256, 0, stream>>>(x_nodes, emb, WQKb, x_cur, xbf_a, qbuf, kbuf);

  u16* xb_cur = xbf_a;
  u16* xb_nxt = xbf_b;
  for (int l = 0; l < L_; ++l) {
    const float* Bl = B + (size_t)l * D_;
    int doqk = (l < L_ - 1) ? 1 : 0;
    const float* WQKn = doqk ? (WQKb + (size_t)(l + 1) * D_ * 64) : WQKb;
    k_attn<<<N_ / 4, 256, 0, stream>>>(indptrN, esortD, srcA, etype, qbuf, kbuf,
                                       slotOf, awbuf);
    k_node<<<N_ / 32, 256, 0, stream>>>(xb_cur, Wtb + (size_t)l * R_ * HK_ * D_,
                                        indptrR, srcR, awbuf, Bl, WQKn, doqk,
                                        x_cur, xb_nxt, qbuf, kbuf);
    u16* tmp = xb_cur; xb_cur = xb_nxt; xb_nxt = tmp;
  }

  k_pool<<<(G_ * D_) / 256, 256, 0, stream>>>(x_cur, pooled);
  k_head<<<G_, 64, 0, stream>>>(pooled, fc1w, fc1b, polw, polb, valw, valb, out);
}